// Round 4
// baseline (704.520 us; speedup 1.0000x reference)
//
#include <hip/hip_runtime.h>

#define NN 100000
#define NE 1600000
#define D 64
#define SCAN_B 1024
#define NBLK ((NN + SCAN_B - 1) / SCAN_B)  // 98
#define BSHIFT 7
#define NPB (1 << BSHIFT)                  // 128 nodes per bucket
#define NBUCK ((NN + NPB - 1) / NPB)       // 782

// ---------- degree histogram ----------
__global__ void deg_kernel(const int* __restrict__ dst, int* __restrict__ deg, int nE) {
    int i = blockIdx.x * blockDim.x + threadIdx.x;
    if (i < nE) atomicAdd(&deg[dst[i]], 1);
}

// ---------- hierarchical exclusive scan: deg -> rowptr ----------
__global__ __launch_bounds__(1024) void scan1_kernel(const int* __restrict__ deg,
                                                     int* __restrict__ rowptr,
                                                     int* __restrict__ bsums) {
    __shared__ int tmp[SCAN_B];
    int t = threadIdx.x;
    int g = blockIdx.x * SCAN_B + t;
    int v = (g < NN) ? deg[g] : 0;
    int x = v;
    tmp[t] = x;
    __syncthreads();
    for (int off = 1; off < SCAN_B; off <<= 1) {
        int y = (t >= off) ? tmp[t - off] : 0;
        __syncthreads();
        x += y;
        tmp[t] = x;
        __syncthreads();
    }
    if (g < NN) rowptr[g] = x - v;
    if (t == SCAN_B - 1) bsums[blockIdx.x] = x;
}

__global__ __launch_bounds__(128) void scan2_kernel(int* __restrict__ bsums) {
    __shared__ int tmp[128];
    int t = threadIdx.x;
    int v = (t < NBLK) ? bsums[t] : 0;
    int x = v;
    tmp[t] = x;
    __syncthreads();
    for (int off = 1; off < 128; off <<= 1) {
        int y = (t >= off) ? tmp[t - off] : 0;
        __syncthreads();
        x += y;
        tmp[t] = x;
        __syncthreads();
    }
    if (t < NBLK) bsums[t] = x - v;
}

__global__ __launch_bounds__(1024) void scan3_kernel(int* __restrict__ rowptr,
                                                     const int* __restrict__ bsums) {
    int g = blockIdx.x * SCAN_B + threadIdx.x;
    if (g < NN) rowptr[g] += bsums[blockIdx.x];
    if (g == 0) rowptr[NN] = NE;
}

// ---------- bucketed CSR fill ----------
// Phase A: scatter packed (src<<BSHIFT | local_dst) into bucket-grouped ebuf.
// Bucket b's region is [rowptr[b<<BSHIFT], rowptr[min((b+1)<<BSHIFT, NN)]) — free from rowptr.
__global__ void binA_kernel(const int* __restrict__ src, const int* __restrict__ dst,
                            const int* __restrict__ rowptr, int* __restrict__ bcursor,
                            int* __restrict__ ebuf, int nE) {
    int i = blockIdx.x * blockDim.x + threadIdx.x;
    if (i < nE) {
        int d = dst[i];
        int s = src[i];
        int b = d >> BSHIFT;
        int p = rowptr[b << BSHIFT] + atomicAdd(&bcursor[b], 1);
        ebuf[p] = (s << BSHIFT) | (d & (NPB - 1));
    }
}

// Phase B: one block per bucket. All writes to any csr row come from exactly this
// block (16KB window -> full-line writebacks); cursors live in LDS.
__global__ __launch_bounds__(256) void binB_kernel(const int* __restrict__ ebuf,
                                                   const int* __restrict__ rowptr,
                                                   int* __restrict__ csr_src) {
    __shared__ int lcur[NPB];
    int b = blockIdx.x;
    int base = b << BSHIFT;
    if (threadIdx.x < NPB) lcur[threadIdx.x] = 0;
    __syncthreads();
    int e0 = rowptr[base];
    int e1 = rowptr[min(base + NPB, NN)];
    for (int e = e0 + threadIdx.x; e < e1; e += 256) {
        int v = ebuf[e];
        int ld = v & (NPB - 1);
        int p = rowptr[base + ld] + atomicAdd(&lcur[ld], 1);
        csr_src[p] = v >> BSHIFT;
    }
}

__global__ void norm_kernel(const int* __restrict__ deg, float* __restrict__ norm, int nN) {
    int i = blockIdx.x * blockDim.x + threadIdx.x;
    if (i < nN) norm[i] = rsqrtf(fmaxf((float)deg[i], 1.0f));
}

// ---------- gather-side aggregation: one wave per dst node, lane = feature ----------
// HOP=1: out[d,j] = norm[d]^2 * sum_e norm[s] * in[s,j]
// HOP=2: out[d,j] = sum_e in[s,j]
template <int HOP>
__global__ __launch_bounds__(256) void gather_kernel(const float* __restrict__ in,
                                                     const int* __restrict__ rowptr,
                                                     const int* __restrict__ csr_src,
                                                     const float* __restrict__ norm,
                                                     float* __restrict__ out, int nN) {
    int node = blockIdx.x * 4 + (threadIdx.x >> 6);
    int lane = threadIdx.x & 63;
    if (node >= nN) return;
    int e = rowptr[node];
    const int end = rowptr[node + 1];
    float acc = 0.0f;
    for (; e + 7 < end; e += 8) {
#pragma unroll
        for (int u = 0; u < 8; ++u) {
            int s = csr_src[e + u];
            float v = in[(size_t)s * D + lane];
            if (HOP == 1) v *= norm[s];
            acc += v;
        }
    }
    for (; e < end; ++e) {
        int s = csr_src[e];
        float v = in[(size_t)s * D + lane];
        if (HOP == 1) v *= norm[s];
        acc += v;
    }
    if (HOP == 1) {
        float nd = norm[node];
        acc *= nd * nd;
    }
    out[(size_t)node * D + lane] = acc;
}

// ---------- fused final norm + FC, 16 rows/block ----------
__global__ __launch_bounds__(256) void fc_kernel(float* __restrict__ h,
                                                 const float* __restrict__ norm,
                                                 const float* __restrict__ W1,
                                                 const float* __restrict__ b1) {
    __shared__ float shW[D][D + 1];
    __shared__ float shX[4][D];
    int tid = threadIdx.x;
    for (int i = tid; i < D * D; i += 256) shW[i / D][i % D] = W1[i];
    int r = tid >> 6;
    int j = tid & 63;
    float bj = b1[j];
    int n0 = blockIdx.x * 16;
    for (int pass = 0; pass < 4; ++pass) {
        int n = n0 + pass * 4 + r;
        __syncthreads();
        shX[r][j] = h[(size_t)n * D + j] * norm[n];
        __syncthreads();
        float acc = bj;
#pragma unroll
        for (int k = 0; k < D; ++k) acc += shX[r][k] * shW[j][k];
        h[(size_t)n * D + j] = acc;
    }
}

extern "C" void kernel_launch(void* const* d_in, const int* in_sizes, int n_in,
                              void* d_out, int out_size, void* d_ws, size_t ws_size,
                              hipStream_t stream) {
    const float* feat = (const float*)d_in[0];
    const int* src    = (const int*)d_in[1];
    const int* dst    = (const int*)d_in[2];
    const float* W1   = (const float*)d_in[3];
    const float* b1   = (const float*)d_in[4];
    float* out        = (float*)d_out;

    // ws layout (4B units):
    // deg[NN] | bcursor[NBUCK] | rowptr[NN+1] | norm[NN] | bsums[NBLK] | csr_src[NE] | t1[NN*D]
    // ebuf (NE ints, bucket-grouped packed edges) aliases t1 (dead until hop 1).
    int*   deg     = (int*)d_ws;
    int*   bcursor = deg + NN;
    int*   rowptr  = bcursor + NBUCK;
    float* norm    = (float*)(rowptr + NN + 1);
    int*   bsums   = (int*)(norm + NN);
    int*   csr_src = bsums + NBLK;
    float* t1      = (float*)(csr_src + NE);
    int*   ebuf    = (int*)t1;

    // zero deg + bcursor (contiguous leading region)
    hipMemsetAsync(d_ws, 0, (size_t)(NN + NBUCK) * sizeof(int), stream);

    deg_kernel<<<(NE + 255) / 256, 256, 0, stream>>>(dst, deg, NE);
    scan1_kernel<<<NBLK, SCAN_B, 0, stream>>>(deg, rowptr, bsums);
    scan2_kernel<<<1, 128, 0, stream>>>(bsums);
    scan3_kernel<<<NBLK, SCAN_B, 0, stream>>>(rowptr, bsums);

    binA_kernel<<<(NE + 255) / 256, 256, 0, stream>>>(src, dst, rowptr, bcursor, ebuf, NE);
    binB_kernel<<<NBUCK, 256, 0, stream>>>(ebuf, rowptr, csr_src);

    norm_kernel<<<(NN + 255) / 256, 256, 0, stream>>>(deg, norm, NN);

    // hop 1: t1[d] = norm[d]^2 * sum norm[s] * feat[s]   (overwrites ebuf — dead now)
    gather_kernel<1><<<(NN + 3) / 4, 256, 0, stream>>>(feat, rowptr, csr_src, norm, t1, NN);
    // hop 2: out[d] = sum t1[s]
    gather_kernel<2><<<(NN + 3) / 4, 256, 0, stream>>>(t1, rowptr, csr_src, norm, out, NN);

    // final: out[n] = (norm[n]*out[n]) @ W1^T + b1, in place
    fc_kernel<<<NN / 16, 256, 0, stream>>>(out, norm, W1, b1);
}

// Round 5
// 247.442 us; speedup vs baseline: 2.8472x; 2.8472x over previous
//
#include <hip/hip_runtime.h>

#define NN 100000
#define NE 1600000
#define D 64
#define SCAN_B 1024
#define BSHIFT 7
#define NPB 128                   // nodes per bucket
#define NBUCK ((NN + NPB - 1) / NPB)   // 782
#define NCHUNK 128                // edge chunks (blocks) in hist/partition
#define CE (NE / NCHUNK)          // 12500 edges per chunk (exact)
#define NH (NBUCK * NCHUNK)       // 100096 hist entries

// ---------- per-chunk bucket histogram (no global atomics) ----------
__global__ __launch_bounds__(256) void hist_kernel(const int* __restrict__ dst,
                                                   int* __restrict__ histG) {
    __shared__ int h[NBUCK];
    for (int i = threadIdx.x; i < NBUCK; i += 256) h[i] = 0;
    __syncthreads();
    const int e0 = blockIdx.x * CE;
    for (int i = e0 + threadIdx.x; i < e0 + CE; i += 256)
        atomicAdd(&h[dst[i] >> BSHIFT], 1);
    __syncthreads();
    for (int i = threadIdx.x; i < NBUCK; i += 256)
        histG[i * NCHUNK + blockIdx.x] = h[i];   // bucket-major for scan
}

// ---------- generic hierarchical exclusive scan (in-place capable) ----------
__global__ __launch_bounds__(1024) void scan1_kernel(const int* __restrict__ in,
                                                     int* __restrict__ out,
                                                     int* __restrict__ bsums, int n) {
    __shared__ int tmp[SCAN_B];
    int t = threadIdx.x;
    int g = blockIdx.x * SCAN_B + t;
    int v = (g < n) ? in[g] : 0;
    int x = v;
    tmp[t] = x;
    __syncthreads();
    for (int off = 1; off < SCAN_B; off <<= 1) {
        int y = (t >= off) ? tmp[t - off] : 0;
        __syncthreads();
        x += y;
        tmp[t] = x;
        __syncthreads();
    }
    if (g < n) out[g] = x - v;
    if (t == SCAN_B - 1) bsums[blockIdx.x] = x;
}

__global__ __launch_bounds__(128) void scan2_kernel(int* __restrict__ bsums, int nblk) {
    __shared__ int tmp[128];
    int t = threadIdx.x;
    int v = (t < nblk) ? bsums[t] : 0;
    int x = v;
    tmp[t] = x;
    __syncthreads();
    for (int off = 1; off < 128; off <<= 1) {
        int y = (t >= off) ? tmp[t - off] : 0;
        __syncthreads();
        x += y;
        tmp[t] = x;
        __syncthreads();
    }
    if (t < nblk) bsums[t] = x - v;
}

__global__ __launch_bounds__(1024) void scan3_kernel(int* __restrict__ out,
                                                     const int* __restrict__ bsums,
                                                     int n, int total) {
    int g = blockIdx.x * SCAN_B + threadIdx.x;
    if (g < n) out[g] += bsums[blockIdx.x];
    if (g == 0) out[n] = total;
}

// ---------- partition: scatter packed edges into bucket regions, LDS cursors ----------
__global__ __launch_bounds__(256) void partW_kernel(const int* __restrict__ src,
                                                    const int* __restrict__ dst,
                                                    const int* __restrict__ histS,
                                                    int* __restrict__ ebuf) {
    __shared__ int base[NBUCK];
    __shared__ int cur[NBUCK];
    for (int i = threadIdx.x; i < NBUCK; i += 256) {
        base[i] = histS[i * NCHUNK + blockIdx.x];
        cur[i] = 0;
    }
    __syncthreads();
    const int e0 = blockIdx.x * CE;
    for (int i = e0 + threadIdx.x; i < e0 + CE; i += 256) {
        int d = dst[i], s = src[i];
        int b = d >> BSHIFT;
        int p = base[b] + atomicAdd(&cur[b], 1);
        ebuf[p] = (s << BSHIFT) | (d & (NPB - 1));   // s < 2^17, fits
    }
}

// ---------- per-bucket degree + norm (no global atomics), writes scan input ----------
__global__ __launch_bounds__(256) void degb_kernel(const int* __restrict__ ebuf,
                                                   const int* __restrict__ histS,
                                                   int* __restrict__ rp,
                                                   float* __restrict__ norm) {
    __shared__ int cnt[NPB];
    int b = blockIdx.x;
    int base = b << BSHIFT;
    if (threadIdx.x < NPB) cnt[threadIdx.x] = 0;
    __syncthreads();
    int e0 = histS[b * NCHUNK];
    int e1 = histS[(b + 1) * NCHUNK];   // last bucket: histS[NH] = NE
    for (int e = e0 + threadIdx.x; e < e1; e += 256)
        atomicAdd(&cnt[ebuf[e] & (NPB - 1)], 1);
    __syncthreads();
    int t = threadIdx.x;
    if (t < NPB && base + t < NN) {
        int c = cnt[t];
        rp[base + t] = c;
        norm[base + t] = rsqrtf(fmaxf((float)c, 1.0f));
    }
}

// ---------- bucket region -> CSR rows (full-line writes, LDS cursors) ----------
__global__ __launch_bounds__(256) void binB_kernel(const int* __restrict__ ebuf,
                                                   const int* __restrict__ histS,
                                                   const int* __restrict__ rowptr,
                                                   int* __restrict__ csr_src) {
    __shared__ int lcur[NPB];
    int b = blockIdx.x;
    int base = b << BSHIFT;
    if (threadIdx.x < NPB) lcur[threadIdx.x] = 0;
    __syncthreads();
    int e0 = histS[b * NCHUNK];
    int e1 = histS[(b + 1) * NCHUNK];
    for (int e = e0 + threadIdx.x; e < e1; e += 256) {
        int v = ebuf[e];
        int ld = v & (NPB - 1);
        int p = rowptr[base + ld] + atomicAdd(&lcur[ld], 1);
        csr_src[p] = v >> BSHIFT;
    }
}

// ---------- gather aggregation: wave=node, 16 lanes x float4, 4 edges/wave ----------
// HOP=1: out[d] = norm[d]^2 * sum_e norm[s] * in[s]
// HOP=2: out[d] = sum_e in[s]
template <int HOP>
__global__ __launch_bounds__(256) void gather_kernel(const float* __restrict__ in,
                                                     const int* __restrict__ rowptr,
                                                     const int* __restrict__ csr_src,
                                                     const float* __restrict__ norm,
                                                     float* __restrict__ out, int nN) {
    int node = blockIdx.x * 4 + (threadIdx.x >> 6);
    int lane = threadIdx.x & 63;
    if (node >= nN) return;
    const int sub = lane >> 4;        // edge slot 0..3
    const int fo  = (lane & 15) * 4;  // feature offset
    const int e0 = rowptr[node];
    const int e1 = rowptr[node + 1];
    float ax = 0.f, ay = 0.f, az = 0.f, aw = 0.f;
    int e = e0;
    for (; e + 8 <= e1; e += 8) {   // 8 edges in flight per wave
        int sA = csr_src[e + sub];
        int sB = csr_src[e + 4 + sub];
        float wA = (HOP == 1) ? norm[sA] : 1.0f;
        float wB = (HOP == 1) ? norm[sB] : 1.0f;
        const float4 vA = *reinterpret_cast<const float4*>(in + (size_t)sA * D + fo);
        const float4 vB = *reinterpret_cast<const float4*>(in + (size_t)sB * D + fo);
        ax += wA * vA.x + wB * vB.x;
        ay += wA * vA.y + wB * vB.y;
        az += wA * vA.z + wB * vB.z;
        aw += wA * vA.w + wB * vB.w;
    }
    for (; e < e1; e += 4) {
        int idx = e + sub;
        if (idx < e1) {
            int s = csr_src[idx];
            float w = (HOP == 1) ? norm[s] : 1.0f;
            const float4 v = *reinterpret_cast<const float4*>(in + (size_t)s * D + fo);
            ax += w * v.x; ay += w * v.y; az += w * v.z; aw += w * v.w;
        }
    }
    // reduce over the 4 edge slots: lanes {l, l^16, l^32, l^48}
    ax += __shfl_xor(ax, 16); ay += __shfl_xor(ay, 16);
    az += __shfl_xor(az, 16); aw += __shfl_xor(aw, 16);
    ax += __shfl_xor(ax, 32); ay += __shfl_xor(ay, 32);
    az += __shfl_xor(az, 32); aw += __shfl_xor(aw, 32);
    if (sub == 0) {
        if (HOP == 1) {
            float nd = norm[node];
            float sc = nd * nd;
            ax *= sc; ay *= sc; az *= sc; aw *= sc;
        }
        float4 r = {ax, ay, az, aw};
        *reinterpret_cast<float4*>(out + (size_t)node * D + fo) = r;
    }
}

// ---------- fused final norm + FC, 16 rows/block ----------
__global__ __launch_bounds__(256) void fc_kernel(float* __restrict__ h,
                                                 const float* __restrict__ norm,
                                                 const float* __restrict__ W1,
                                                 const float* __restrict__ b1) {
    __shared__ float shW[D][D + 1];
    __shared__ float shX[4][D];
    int tid = threadIdx.x;
    for (int i = tid; i < D * D; i += 256) shW[i / D][i % D] = W1[i];
    int r = tid >> 6;
    int j = tid & 63;
    float bj = b1[j];
    int n0 = blockIdx.x * 16;
    for (int pass = 0; pass < 4; ++pass) {
        int n = n0 + pass * 4 + r;
        __syncthreads();
        shX[r][j] = h[(size_t)n * D + j] * norm[n];
        __syncthreads();
        float acc = bj;
#pragma unroll
        for (int k = 0; k < D; ++k) acc += shX[r][k] * shW[j][k];
        h[(size_t)n * D + j] = acc;
    }
}

extern "C" void kernel_launch(void* const* d_in, const int* in_sizes, int n_in,
                              void* d_out, int out_size, void* d_ws, size_t ws_size,
                              hipStream_t stream) {
    const float* feat = (const float*)d_in[0];
    const int* src    = (const int*)d_in[1];
    const int* dst    = (const int*)d_in[2];
    const float* W1   = (const float*)d_in[3];
    const float* b1   = (const float*)d_in[4];
    float* out        = (float*)d_out;

    // ws layout (4B units), no memsets needed (every word written before read):
    // rowptr[NN+1] | norm[NN] | bsums[128] | histS[NH+1] | csr_src[NE] | t1[NN*D]
    // ebuf (NE ints) aliases t1 (dead until gather1 overwrites it).
    int*   rowptr = (int*)d_ws;
    float* norm   = (float*)(rowptr + NN + 1);
    int*   bsums  = (int*)(norm + NN);
    int*   histS  = bsums + 128;
    int*   csr_src = histS + NH + 1;
    float* t1     = (float*)(csr_src + NE);
    int*   ebuf   = (int*)t1;

    const int nblkH = (NH + SCAN_B - 1) / SCAN_B;   // 98
    const int nblkN = (NN + SCAN_B - 1) / SCAN_B;   // 98

    // CSR build, zero global atomics:
    hist_kernel<<<NCHUNK, 256, 0, stream>>>(dst, histS);            // histS <- raw counts
    scan1_kernel<<<nblkH, SCAN_B, 0, stream>>>(histS, histS, bsums, NH);  // in-place scan
    scan2_kernel<<<1, 128, 0, stream>>>(bsums, nblkH);
    scan3_kernel<<<nblkH, SCAN_B, 0, stream>>>(histS, bsums, NH, NE);
    partW_kernel<<<NCHUNK, 256, 0, stream>>>(src, dst, histS, ebuf);
    degb_kernel<<<NBUCK, 256, 0, stream>>>(ebuf, histS, rowptr, norm);
    scan1_kernel<<<nblkN, SCAN_B, 0, stream>>>(rowptr, rowptr, bsums, NN);
    scan2_kernel<<<1, 128, 0, stream>>>(bsums, nblkN);
    scan3_kernel<<<nblkN, SCAN_B, 0, stream>>>(rowptr, bsums, NN, NE);
    binB_kernel<<<NBUCK, 256, 0, stream>>>(ebuf, histS, rowptr, csr_src);

    // hop 1: t1[d] = norm[d]^2 * sum norm[s] * feat[s]   (overwrites ebuf — dead now)
    gather_kernel<1><<<(NN + 3) / 4, 256, 0, stream>>>(feat, rowptr, csr_src, norm, t1, NN);
    // hop 2: out[d] = sum t1[s]
    gather_kernel<2><<<(NN + 3) / 4, 256, 0, stream>>>(t1, rowptr, csr_src, norm, out, NN);

    // final: out[n] = (norm[n]*out[n]) @ W1^T + b1, in place
    fc_kernel<<<NN / 16, 256, 0, stream>>>(out, norm, W1, b1);
}

// Round 6
// 222.071 us; speedup vs baseline: 3.1725x; 1.1142x over previous
//
#include <hip/hip_runtime.h>

#define NN 100000
#define NE 1600000
#define D 64
#define SCAN_B 1024
#define BSHIFT 7
#define NPB 128                        // nodes per bucket
#define NBUCK ((NN + NPB - 1) / NPB)   // 782
#define NCHUNK 128                     // edge chunks in hist/partition
#define CE (NE / NCHUNK)               // 12500 edges per chunk (exact)
#define NH (NBUCK * NCHUNK)            // 100096

typedef unsigned int uint32;
typedef unsigned short ushort16;

__device__ __forceinline__ uint32 f2bf(float f) {   // round-to-nearest-even
    union { float f; uint32 i; } c; c.f = f;
    return (c.i + 0x7FFFu + ((c.i >> 16) & 1u)) >> 16;
}

// ---------- feat (f32) -> fb (bf16) ----------
__global__ __launch_bounds__(256) void cvt_kernel(const float* __restrict__ feat,
                                                  ushort16* __restrict__ fb) {
    int i = blockIdx.x * 256 + threadIdx.x;            // grid covers NN*D/4 exactly
    float4 v = reinterpret_cast<const float4*>(feat)[i];
    uint2 o;
    o.x = f2bf(v.x) | (f2bf(v.y) << 16);
    o.y = f2bf(v.z) | (f2bf(v.w) << 16);
    reinterpret_cast<uint2*>(fb)[i] = o;
}

// ---------- per-chunk bucket histogram (no global atomics) ----------
__global__ __launch_bounds__(256) void hist_kernel(const int* __restrict__ dst,
                                                   int* __restrict__ histG) {
    __shared__ int h[NBUCK];
    for (int i = threadIdx.x; i < NBUCK; i += 256) h[i] = 0;
    __syncthreads();
    const int e0 = blockIdx.x * CE;
    for (int i = e0 + threadIdx.x; i < e0 + CE; i += 256)
        atomicAdd(&h[dst[i] >> BSHIFT], 1);
    __syncthreads();
    for (int i = threadIdx.x; i < NBUCK; i += 256)
        histG[i * NCHUNK + blockIdx.x] = h[i];
}

// ---------- generic hierarchical exclusive scan ----------
__global__ __launch_bounds__(1024) void scan1_kernel(const int* __restrict__ in,
                                                     int* __restrict__ out,
                                                     int* __restrict__ bsums, int n) {
    __shared__ int tmp[SCAN_B];
    int t = threadIdx.x;
    int g = blockIdx.x * SCAN_B + t;
    int v = (g < n) ? in[g] : 0;
    int x = v;
    tmp[t] = x;
    __syncthreads();
    for (int off = 1; off < SCAN_B; off <<= 1) {
        int y = (t >= off) ? tmp[t - off] : 0;
        __syncthreads();
        x += y;
        tmp[t] = x;
        __syncthreads();
    }
    if (g < n) out[g] = x - v;
    if (t == SCAN_B - 1) bsums[blockIdx.x] = x;
}

__global__ __launch_bounds__(128) void scan2_kernel(int* __restrict__ bsums, int nblk) {
    __shared__ int tmp[128];
    int t = threadIdx.x;
    int v = (t < nblk) ? bsums[t] : 0;
    int x = v;
    tmp[t] = x;
    __syncthreads();
    for (int off = 1; off < 128; off <<= 1) {
        int y = (t >= off) ? tmp[t - off] : 0;
        __syncthreads();
        x += y;
        tmp[t] = x;
        __syncthreads();
    }
    if (t < nblk) bsums[t] = x - v;
}

__global__ __launch_bounds__(1024) void scan3_kernel(int* __restrict__ out,
                                                     const int* __restrict__ bsums,
                                                     int n, int total) {
    int g = blockIdx.x * SCAN_B + threadIdx.x;
    if (g < n) out[g] += bsums[blockIdx.x];
    if (g == 0) out[n] = total;
}

// ---------- partition: packed edges into bucket regions, LDS cursors ----------
__global__ __launch_bounds__(256) void partW_kernel(const int* __restrict__ src,
                                                    const int* __restrict__ dst,
                                                    const int* __restrict__ histS,
                                                    int* __restrict__ ebuf) {
    __shared__ int base[NBUCK];
    __shared__ int cur[NBUCK];
    for (int i = threadIdx.x; i < NBUCK; i += 256) {
        base[i] = histS[i * NCHUNK + blockIdx.x];
        cur[i] = 0;
    }
    __syncthreads();
    const int e0 = blockIdx.x * CE;
    for (int i = e0 + threadIdx.x; i < e0 + CE; i += 256) {
        int d = dst[i], s = src[i];
        int b = d >> BSHIFT;
        int p = base[b] + atomicAdd(&cur[b], 1);
        ebuf[p] = (s << BSHIFT) | (d & (NPB - 1));
    }
}

// ---------- per-bucket degree + norm ----------
__global__ __launch_bounds__(256) void degb_kernel(const int* __restrict__ ebuf,
                                                   const int* __restrict__ histS,
                                                   int* __restrict__ rp,
                                                   float* __restrict__ norm) {
    __shared__ int cnt[NPB];
    int b = blockIdx.x;
    int base = b << BSHIFT;
    if (threadIdx.x < NPB) cnt[threadIdx.x] = 0;
    __syncthreads();
    int e0 = histS[b * NCHUNK];
    int e1 = histS[(b + 1) * NCHUNK];
    for (int e = e0 + threadIdx.x; e < e1; e += 256)
        atomicAdd(&cnt[ebuf[e] & (NPB - 1)], 1);
    __syncthreads();
    int t = threadIdx.x;
    if (t < NPB && base + t < NN) {
        int c = cnt[t];
        rp[base + t] = c;
        norm[base + t] = rsqrtf(fmaxf((float)c, 1.0f));
    }
}

// ---------- bucket region -> CSR rows ----------
__global__ __launch_bounds__(256) void binB_kernel(const int* __restrict__ ebuf,
                                                   const int* __restrict__ histS,
                                                   const int* __restrict__ rowptr,
                                                   int* __restrict__ csr_src) {
    __shared__ int lcur[NPB];
    int b = blockIdx.x;
    int base = b << BSHIFT;
    if (threadIdx.x < NPB) lcur[threadIdx.x] = 0;
    __syncthreads();
    int e0 = histS[b * NCHUNK];
    int e1 = histS[(b + 1) * NCHUNK];
    for (int e = e0 + threadIdx.x; e < e1; e += 256) {
        int v = ebuf[e];
        int ld = v & (NPB - 1);
        int p = rowptr[base + ld] + atomicAdd(&lcur[ld], 1);
        csr_src[p] = v >> BSHIFT;
    }
}

// unpack-accumulate 8 bf16 (uint4) with weight W into a0..a7
#define ACC8(Rr, W)                                    \
    a0 += (W) * __uint_as_float((Rr).x << 16);         \
    a1 += (W) * __uint_as_float((Rr).x & 0xFFFF0000u); \
    a2 += (W) * __uint_as_float((Rr).y << 16);         \
    a3 += (W) * __uint_as_float((Rr).y & 0xFFFF0000u); \
    a4 += (W) * __uint_as_float((Rr).z << 16);         \
    a5 += (W) * __uint_as_float((Rr).z & 0xFFFF0000u); \
    a6 += (W) * __uint_as_float((Rr).w << 16);         \
    a7 += (W) * __uint_as_float((Rr).w & 0xFFFF0000u);

#define SLOT_REDUCE()                                              \
    _Pragma("unroll")                                              \
    for (int off = 8; off <= 32; off <<= 1) {                      \
        a0 += __shfl_xor(a0, off); a1 += __shfl_xor(a1, off);      \
        a2 += __shfl_xor(a2, off); a3 += __shfl_xor(a3, off);      \
        a4 += __shfl_xor(a4, off); a5 += __shfl_xor(a5, off);      \
        a6 += __shfl_xor(a6, off); a7 += __shfl_xor(a7, off);      \
    }

// ---------- hop 1: t1b[d] = bf16( norm[d]^2 * sum_e norm[s]*fb[s] ) ----------
// wave = node; 8 edge slots x 8 lanes x 16B (8 bf16); f32 accumulate.
__global__ __launch_bounds__(256) void gather1_kernel(const ushort16* __restrict__ fb,
                                                      const int* __restrict__ rowptr,
                                                      const int* __restrict__ csr,
                                                      const float* __restrict__ norm,
                                                      ushort16* __restrict__ t1b) {
    const int node = blockIdx.x * 4 + (threadIdx.x >> 6);
    const int lane = threadIdx.x & 63;
    const int slot = lane >> 3;
    const int fo = (lane & 7) * 8;
    int e = rowptr[node];
    const int e1 = rowptr[node + 1];
    float a0 = 0, a1 = 0, a2 = 0, a3 = 0, a4 = 0, a5 = 0, a6 = 0, a7 = 0;
    for (; e + 16 <= e1; e += 16) {
        int sA = csr[e + slot];
        int sB = csr[e + 8 + slot];
        float wA = norm[sA];
        float wB = norm[sB];
        uint4 rA = *reinterpret_cast<const uint4*>(fb + (size_t)sA * D + fo);
        uint4 rB = *reinterpret_cast<const uint4*>(fb + (size_t)sB * D + fo);
        ACC8(rA, wA)
        ACC8(rB, wB)
    }
    for (; e + 8 <= e1; e += 8) {
        int s = csr[e + slot];
        float w = norm[s];
        uint4 r = *reinterpret_cast<const uint4*>(fb + (size_t)s * D + fo);
        ACC8(r, w)
    }
    if (e + slot < e1) {
        int s = csr[e + slot];
        float w = norm[s];
        uint4 r = *reinterpret_cast<const uint4*>(fb + (size_t)s * D + fo);
        ACC8(r, w)
    }
    SLOT_REDUCE()
    if (slot == 0) {
        const float nd = norm[node];
        const float sc = nd * nd;
        uint4 o;
        o.x = f2bf(a0 * sc) | (f2bf(a1 * sc) << 16);
        o.y = f2bf(a2 * sc) | (f2bf(a3 * sc) << 16);
        o.z = f2bf(a4 * sc) | (f2bf(a5 * sc) << 16);
        o.w = f2bf(a6 * sc) | (f2bf(a7 * sc) << 16);
        *reinterpret_cast<uint4*>(t1b + (size_t)node * D + fo) = o;
    }
}

// ---------- hop 2 + fused FC:  out[n] = (norm[n] * sum_e t1b[s]) @ W1^T + b1 ----------
__global__ __launch_bounds__(256) void gather2_kernel(const ushort16* __restrict__ t1b,
                                                      const int* __restrict__ rowptr,
                                                      const int* __restrict__ csr,
                                                      const float* __restrict__ norm,
                                                      const float* __restrict__ W1,
                                                      const float* __restrict__ b1,
                                                      float* __restrict__ out) {
    __shared__ float shW[D][D + 1];
    __shared__ float shX[4][D];
    const int tid = threadIdx.x;
    for (int i = tid; i < D * D; i += 256) shW[i >> 6][i & 63] = W1[i];
    const int wid = tid >> 6;
    const int node = blockIdx.x * 4 + wid;
    const int lane = tid & 63;
    const int slot = lane >> 3;
    const int fo = (lane & 7) * 8;
    int e = rowptr[node];
    const int e1 = rowptr[node + 1];
    float a0 = 0, a1 = 0, a2 = 0, a3 = 0, a4 = 0, a5 = 0, a6 = 0, a7 = 0;
    for (; e + 16 <= e1; e += 16) {
        int sA = csr[e + slot];
        int sB = csr[e + 8 + slot];
        uint4 rA = *reinterpret_cast<const uint4*>(t1b + (size_t)sA * D + fo);
        uint4 rB = *reinterpret_cast<const uint4*>(t1b + (size_t)sB * D + fo);
        ACC8(rA, 1.0f)
        ACC8(rB, 1.0f)
    }
    for (; e + 8 <= e1; e += 8) {
        int s = csr[e + slot];
        uint4 r = *reinterpret_cast<const uint4*>(t1b + (size_t)s * D + fo);
        ACC8(r, 1.0f)
    }
    if (e + slot < e1) {
        int s = csr[e + slot];
        uint4 r = *reinterpret_cast<const uint4*>(t1b + (size_t)s * D + fo);
        ACC8(r, 1.0f)
    }
    SLOT_REDUCE()
    if (slot == 0) {
        const float nd = norm[node];
        shX[wid][fo + 0] = a0 * nd; shX[wid][fo + 1] = a1 * nd;
        shX[wid][fo + 2] = a2 * nd; shX[wid][fo + 3] = a3 * nd;
        shX[wid][fo + 4] = a4 * nd; shX[wid][fo + 5] = a5 * nd;
        shX[wid][fo + 6] = a6 * nd; shX[wid][fo + 7] = a7 * nd;
    }
    __syncthreads();   // covers shW staging + shX writes; all 256 threads reach (exact grid)
    float o = b1[lane];
#pragma unroll
    for (int k = 0; k < D; ++k) o += shX[wid][k] * shW[lane][k];
    out[(size_t)node * D + lane] = o;
}

extern "C" void kernel_launch(void* const* d_in, const int* in_sizes, int n_in,
                              void* d_out, int out_size, void* d_ws, size_t ws_size,
                              hipStream_t stream) {
    const float* feat = (const float*)d_in[0];
    const int* src    = (const int*)d_in[1];
    const int* dst    = (const int*)d_in[2];
    const float* W1   = (const float*)d_in[3];
    const float* b1   = (const float*)d_in[4];
    float* out        = (float*)d_out;

    // ws layout (4B units, 16B-aligned regions):
    // rowptr[100004] | norm[100000] | bsums[128] | histS[100100] | csr_src[NE]
    // | fb[NN*D ushort = 3.2M ints] | X: union{ ebuf[NE ints], t1b[NN*D ushort] } (3.2M ints)
    // total ~33.2 MB; ebuf dead after binB, t1b aliases it.
    int*      rowptr = (int*)d_ws;
    float*    norm   = (float*)(rowptr + 100004);
    int*      bsums  = (int*)(norm + 100000);
    int*      histS  = bsums + 128;
    int*      csr_src = histS + 100100;
    ushort16* fb     = (ushort16*)(csr_src + NE);
    int*      ebuf   = (int*)(fb + (size_t)NN * D);
    ushort16* t1b    = (ushort16*)ebuf;

    const int nblkH = (NH + SCAN_B - 1) / SCAN_B;   // 98
    const int nblkN = (NN + SCAN_B - 1) / SCAN_B;   // 98

    cvt_kernel<<<NN * D / 4 / 256, 256, 0, stream>>>(feat, fb);   // 6250 blocks, exact

    hist_kernel<<<NCHUNK, 256, 0, stream>>>(dst, histS);
    scan1_kernel<<<nblkH, SCAN_B, 0, stream>>>(histS, histS, bsums, NH);
    scan2_kernel<<<1, 128, 0, stream>>>(bsums, nblkH);
    scan3_kernel<<<nblkH, SCAN_B, 0, stream>>>(histS, bsums, NH, NE);
    partW_kernel<<<NCHUNK, 256, 0, stream>>>(src, dst, histS, ebuf);
    degb_kernel<<<NBUCK, 256, 0, stream>>>(ebuf, histS, rowptr, norm);
    scan1_kernel<<<nblkN, SCAN_B, 0, stream>>>(rowptr, rowptr, bsums, NN);
    scan2_kernel<<<1, 128, 0, stream>>>(bsums, nblkN);
    scan3_kernel<<<nblkN, SCAN_B, 0, stream>>>(rowptr, bsums, NN, NE);
    binB_kernel<<<NBUCK, 256, 0, stream>>>(ebuf, histS, rowptr, csr_src);

    // hop 1 (reads fb bf16, writes t1b bf16 — overwrites ebuf, dead now)
    gather1_kernel<<<NN / 4, 256, 0, stream>>>(fb, rowptr, csr_src, norm, t1b);
    // hop 2 + fused norm + FC (reads t1b bf16, writes f32 out)
    gather2_kernel<<<NN / 4, 256, 0, stream>>>(t1b, rowptr, csr_src, norm, W1, b1, out);
}

// Round 7
// 191.075 us; speedup vs baseline: 3.6871x; 1.1622x over previous
//
#include <hip/hip_runtime.h>

#define NN 100000
#define NE 1600000
#define D 64
#define SCAN_B 1024
#define BSHIFT 7
#define NPB 128                        // nodes per bucket
#define NBUCK ((NN + NPB - 1) / NPB)   // 782
#define NCHUNK 128                     // edge chunks in hist/partition
#define CE (NE / NCHUNK)               // 12500 edges per chunk (exact)
#define NH (NBUCK * NCHUNK)            // 100096

typedef unsigned int uint32;
typedef unsigned short ushort16;
typedef __attribute__((ext_vector_type(8))) short bf16x8;
typedef __attribute__((ext_vector_type(4))) float f32x4;

__device__ __forceinline__ uint32 f2bf(float f) {   // round-to-nearest-even
    union { float f; uint32 i; } c; c.f = f;
    return (c.i + 0x7FFFu + ((c.i >> 16) & 1u)) >> 16;
}

// ---------- feat (f32) -> fb (bf16) ----------
__global__ __launch_bounds__(256) void cvt_kernel(const float* __restrict__ feat,
                                                  ushort16* __restrict__ fb) {
    int i = blockIdx.x * 256 + threadIdx.x;            // grid covers NN*D/4 exactly
    float4 v = reinterpret_cast<const float4*>(feat)[i];
    uint2 o;
    o.x = f2bf(v.x) | (f2bf(v.y) << 16);
    o.y = f2bf(v.z) | (f2bf(v.w) << 16);
    reinterpret_cast<uint2*>(fb)[i] = o;
}

// ---------- per-chunk bucket histogram (no global atomics) ----------
__global__ __launch_bounds__(256) void hist_kernel(const int* __restrict__ dst,
                                                   int* __restrict__ histG) {
    __shared__ int h[NBUCK];
    for (int i = threadIdx.x; i < NBUCK; i += 256) h[i] = 0;
    __syncthreads();
    const int e0 = blockIdx.x * CE;
    for (int i = e0 + threadIdx.x; i < e0 + CE; i += 256)
        atomicAdd(&h[dst[i] >> BSHIFT], 1);
    __syncthreads();
    for (int i = threadIdx.x; i < NBUCK; i += 256)
        histG[i * NCHUNK + blockIdx.x] = h[i];
}

// ---------- generic hierarchical exclusive scan ----------
__global__ __launch_bounds__(1024) void scan1_kernel(const int* __restrict__ in,
                                                     int* __restrict__ out,
                                                     int* __restrict__ bsums, int n) {
    __shared__ int tmp[SCAN_B];
    int t = threadIdx.x;
    int g = blockIdx.x * SCAN_B + t;
    int v = (g < n) ? in[g] : 0;
    int x = v;
    tmp[t] = x;
    __syncthreads();
    for (int off = 1; off < SCAN_B; off <<= 1) {
        int y = (t >= off) ? tmp[t - off] : 0;
        __syncthreads();
        x += y;
        tmp[t] = x;
        __syncthreads();
    }
    if (g < n) out[g] = x - v;
    if (t == SCAN_B - 1) bsums[blockIdx.x] = x;
}

__global__ __launch_bounds__(128) void scan2_kernel(int* __restrict__ bsums, int nblk) {
    __shared__ int tmp[128];
    int t = threadIdx.x;
    int v = (t < nblk) ? bsums[t] : 0;
    int x = v;
    tmp[t] = x;
    __syncthreads();
    for (int off = 1; off < 128; off <<= 1) {
        int y = (t >= off) ? tmp[t - off] : 0;
        __syncthreads();
        x += y;
        tmp[t] = x;
        __syncthreads();
    }
    if (t < nblk) bsums[t] = x - v;
}

__global__ __launch_bounds__(1024) void scan3_kernel(int* __restrict__ out,
                                                     const int* __restrict__ bsums,
                                                     int n, int total) {
    int g = blockIdx.x * SCAN_B + threadIdx.x;
    if (g < n) out[g] += bsums[blockIdx.x];
    if (g == 0) out[n] = total;
}

// ---------- partition: packed edges into bucket regions, LDS cursors ----------
__global__ __launch_bounds__(256) void partW_kernel(const int* __restrict__ src,
                                                    const int* __restrict__ dst,
                                                    const int* __restrict__ histS,
                                                    int* __restrict__ ebuf) {
    __shared__ int base[NBUCK];
    __shared__ int cur[NBUCK];
    for (int i = threadIdx.x; i < NBUCK; i += 256) {
        base[i] = histS[i * NCHUNK + blockIdx.x];
        cur[i] = 0;
    }
    __syncthreads();
    const int e0 = blockIdx.x * CE;
    for (int i = e0 + threadIdx.x; i < e0 + CE; i += 256) {
        int d = dst[i], s = src[i];
        int b = d >> BSHIFT;
        int p = base[b] + atomicAdd(&cur[b], 1);
        ebuf[p] = (s << BSHIFT) | (d & (NPB - 1));
    }
}

// ---------- per-bucket degree + norm ----------
__global__ __launch_bounds__(256) void degb_kernel(const int* __restrict__ ebuf,
                                                   const int* __restrict__ histS,
                                                   int* __restrict__ rp,
                                                   float* __restrict__ norm) {
    __shared__ int cnt[NPB];
    int b = blockIdx.x;
    int base = b << BSHIFT;
    if (threadIdx.x < NPB) cnt[threadIdx.x] = 0;
    __syncthreads();
    int e0 = histS[b * NCHUNK];
    int e1 = histS[(b + 1) * NCHUNK];
    for (int e = e0 + threadIdx.x; e < e1; e += 256)
        atomicAdd(&cnt[ebuf[e] & (NPB - 1)], 1);
    __syncthreads();
    int t = threadIdx.x;
    if (t < NPB && base + t < NN) {
        int c = cnt[t];
        rp[base + t] = c;
        norm[base + t] = rsqrtf(fmaxf((float)c, 1.0f));
    }
}

// ---------- bucket region -> CSR rows ----------
__global__ __launch_bounds__(256) void binB_kernel(const int* __restrict__ ebuf,
                                                   const int* __restrict__ histS,
                                                   const int* __restrict__ rowptr,
                                                   int* __restrict__ csr_src) {
    __shared__ int lcur[NPB];
    int b = blockIdx.x;
    int base = b << BSHIFT;
    if (threadIdx.x < NPB) lcur[threadIdx.x] = 0;
    __syncthreads();
    int e0 = histS[b * NCHUNK];
    int e1 = histS[(b + 1) * NCHUNK];
    for (int e = e0 + threadIdx.x; e < e1; e += 256) {
        int v = ebuf[e];
        int ld = v & (NPB - 1);
        int p = rowptr[base + ld] + atomicAdd(&lcur[ld], 1);
        csr_src[p] = v >> BSHIFT;
    }
}

// unpack-accumulate 8 bf16 (uint4) with weight W into a0..a7
#define ACC8(Rr, W)                                    \
    a0 += (W) * __uint_as_float((Rr).x << 16);         \
    a1 += (W) * __uint_as_float((Rr).x & 0xFFFF0000u); \
    a2 += (W) * __uint_as_float((Rr).y << 16);         \
    a3 += (W) * __uint_as_float((Rr).y & 0xFFFF0000u); \
    a4 += (W) * __uint_as_float((Rr).z << 16);         \
    a5 += (W) * __uint_as_float((Rr).z & 0xFFFF0000u); \
    a6 += (W) * __uint_as_float((Rr).w << 16);         \
    a7 += (W) * __uint_as_float((Rr).w & 0xFFFF0000u);

#define SLOT_REDUCE()                                              \
    _Pragma("unroll")                                              \
    for (int off = 8; off <= 32; off <<= 1) {                      \
        a0 += __shfl_xor(a0, off); a1 += __shfl_xor(a1, off);      \
        a2 += __shfl_xor(a2, off); a3 += __shfl_xor(a3, off);      \
        a4 += __shfl_xor(a4, off); a5 += __shfl_xor(a5, off);      \
        a6 += __shfl_xor(a6, off); a7 += __shfl_xor(a7, off);      \
    }

// ---------- gather hops (bf16 in, bf16 out, f32 accumulate) ----------
// HOP=1: out[d] = bf16( norm[d]^2 * sum_e norm[s] * in[s] )
// HOP=2: out[d] = bf16( norm[d]   * sum_e in[s] )
// wave = node; 8 edge slots x 8 lanes x 16B (8 bf16).
template <int HOP>
__global__ __launch_bounds__(256) void gather_kernel(const ushort16* __restrict__ in,
                                                     const int* __restrict__ rowptr,
                                                     const int* __restrict__ csr,
                                                     const float* __restrict__ norm,
                                                     ushort16* __restrict__ outb) {
    const int node = blockIdx.x * 4 + (threadIdx.x >> 6);
    const int lane = threadIdx.x & 63;
    const int slot = lane >> 3;
    const int fo = (lane & 7) * 8;
    int e = rowptr[node];
    const int e1 = rowptr[node + 1];
    float a0 = 0, a1 = 0, a2 = 0, a3 = 0, a4 = 0, a5 = 0, a6 = 0, a7 = 0;
    for (; e + 16 <= e1; e += 16) {
        int sA = csr[e + slot];
        int sB = csr[e + 8 + slot];
        float wA = (HOP == 1) ? norm[sA] : 1.0f;
        float wB = (HOP == 1) ? norm[sB] : 1.0f;
        uint4 rA = *reinterpret_cast<const uint4*>(in + (size_t)sA * D + fo);
        uint4 rB = *reinterpret_cast<const uint4*>(in + (size_t)sB * D + fo);
        ACC8(rA, wA)
        ACC8(rB, wB)
    }
    for (; e + 8 <= e1; e += 8) {
        int s = csr[e + slot];
        float w = (HOP == 1) ? norm[s] : 1.0f;
        uint4 r = *reinterpret_cast<const uint4*>(in + (size_t)s * D + fo);
        ACC8(r, w)
    }
    if (e + slot < e1) {
        int s = csr[e + slot];
        float w = (HOP == 1) ? norm[s] : 1.0f;
        uint4 r = *reinterpret_cast<const uint4*>(in + (size_t)s * D + fo);
        ACC8(r, w)
    }
    SLOT_REDUCE()
    if (slot == 0) {
        const float nd = norm[node];
        const float sc = (HOP == 1) ? nd * nd : nd;
        uint4 o;
        o.x = f2bf(a0 * sc) | (f2bf(a1 * sc) << 16);
        o.y = f2bf(a2 * sc) | (f2bf(a3 * sc) << 16);
        o.z = f2bf(a4 * sc) | (f2bf(a5 * sc) << 16);
        o.w = f2bf(a6 * sc) | (f2bf(a7 * sc) << 16);
        *reinterpret_cast<uint4*>(outb + (size_t)node * D + fo) = o;
    }
}

// ---------- FC via MFMA: out[100000x64] = H2n(bf16) @ W1^T + b1 ----------
// One wave per 16 nodes. A = H2n tile 16x64; B[k][n] = W1[n][k] (a W1 ROW is
// contiguous in k — perfect for the B fragment). 4 N-tiles x 2 K-steps = 8
// v_mfma_f32_16x16x32_bf16. Fragment layouts (gfx950):
//   A: lane l -> row m=l&15, k=(l>>4)*8+i   (8 bf16, one uint4 load)
//   B: lane l -> col n=l&15, k=(l>>4)*8+i   (8 f32 from W1 row, cvt to bf16)
//   C/D: col=lane&15, row=(lane>>4)*4+reg   [measured m89/m91]
__device__ __forceinline__ bf16x8 cvt8(const float* p) {
    float4 lo = *reinterpret_cast<const float4*>(p);
    float4 hi = *reinterpret_cast<const float4*>(p + 4);
    bf16x8 r;
    r[0] = (short)f2bf(lo.x); r[1] = (short)f2bf(lo.y);
    r[2] = (short)f2bf(lo.z); r[3] = (short)f2bf(lo.w);
    r[4] = (short)f2bf(hi.x); r[5] = (short)f2bf(hi.y);
    r[6] = (short)f2bf(hi.z); r[7] = (short)f2bf(hi.w);
    return r;
}

__global__ __launch_bounds__(256) void fc_mfma_kernel(const ushort16* __restrict__ h2b,
                                                      const float* __restrict__ W1,
                                                      const float* __restrict__ b1,
                                                      float* __restrict__ out) {
    const int wid = threadIdx.x >> 6;
    const int lane = threadIdx.x & 63;
    const int node0 = (blockIdx.x * 4 + wid) * 16;
    if (node0 >= NN) return;
    const int m = lane & 15;
    const int kg = lane >> 4;
    const unsigned short* hrow = reinterpret_cast<const unsigned short*>(h2b)
                                 + (size_t)(node0 + m) * D + kg * 8;
    bf16x8 aF0 = *reinterpret_cast<const bf16x8*>(hrow);        // k in [0,32)
    bf16x8 aF1 = *reinterpret_cast<const bf16x8*>(hrow + 32);   // k in [32,64)
#pragma unroll
    for (int t = 0; t < 4; ++t) {
        const float* wrow = W1 + (size_t)(t * 16 + m) * D + kg * 8;
        bf16x8 bF0 = cvt8(wrow);
        bf16x8 bF1 = cvt8(wrow + 32);
        f32x4 acc = {0.f, 0.f, 0.f, 0.f};
        acc = __builtin_amdgcn_mfma_f32_16x16x32_bf16(aF0, bF0, acc, 0, 0, 0);
        acc = __builtin_amdgcn_mfma_f32_16x16x32_bf16(aF1, bF1, acc, 0, 0, 0);
        const int col = t * 16 + m;           // output feature j
        const float bias = b1[col];
#pragma unroll
        for (int r = 0; r < 4; ++r) {
            int row = kg * 4 + r;             // node within tile
            out[(size_t)(node0 + row) * D + col] = acc[r] + bias;
        }
    }
}

extern "C" void kernel_launch(void* const* d_in, const int* in_sizes, int n_in,
                              void* d_out, int out_size, void* d_ws, size_t ws_size,
                              hipStream_t stream) {
    const float* feat = (const float*)d_in[0];
    const int* src    = (const int*)d_in[1];
    const int* dst    = (const int*)d_in[2];
    const float* W1   = (const float*)d_in[3];
    const float* b1   = (const float*)d_in[4];
    float* out        = (float*)d_out;

    // ws layout (4B units, 16B-aligned regions):
    // rowptr[100004] | norm[100000] | bsums[128] | histS[100100] | csr_src[NE]
    // | A: union{ fb bf16[NN*D], t2b bf16[NN*D] } | B: union{ ebuf[NE], t1b bf16[NN*D] }
    // Lifetimes: fb live cvt..gather1; ebuf live partW..binB; t1b live gather1..gather2
    // (aliases ebuf, dead); t2b live gather2..fc (aliases fb, dead).
    int*      rowptr = (int*)d_ws;
    float*    norm   = (float*)(rowptr + 100004);
    int*      bsums  = (int*)(norm + 100000);
    int*      histS  = bsums + 128;
    int*      csr_src = histS + 100100;
    ushort16* fb     = (ushort16*)(csr_src + NE);
    int*      ebuf   = (int*)(fb + (size_t)NN * D);
    ushort16* t1b    = (ushort16*)ebuf;
    ushort16* t2b    = fb;

    const int nblkH = (NH + SCAN_B - 1) / SCAN_B;   // 98
    const int nblkN = (NN + SCAN_B - 1) / SCAN_B;   // 98

    cvt_kernel<<<NN * D / 4 / 256, 256, 0, stream>>>(feat, fb);   // 6250 blocks, exact

    hist_kernel<<<NCHUNK, 256, 0, stream>>>(dst, histS);
    scan1_kernel<<<nblkH, SCAN_B, 0, stream>>>(histS, histS, bsums, NH);
    scan2_kernel<<<1, 128, 0, stream>>>(bsums, nblkH);
    scan3_kernel<<<nblkH, SCAN_B, 0, stream>>>(histS, bsums, NH, NE);
    partW_kernel<<<NCHUNK, 256, 0, stream>>>(src, dst, histS, ebuf);
    degb_kernel<<<NBUCK, 256, 0, stream>>>(ebuf, histS, rowptr, norm);
    scan1_kernel<<<nblkN, SCAN_B, 0, stream>>>(rowptr, rowptr, bsums, NN);
    scan2_kernel<<<1, 128, 0, stream>>>(bsums, nblkN);
    scan3_kernel<<<nblkN, SCAN_B, 0, stream>>>(rowptr, bsums, NN, NE);
    binB_kernel<<<NBUCK, 256, 0, stream>>>(ebuf, histS, rowptr, csr_src);

    // hop 1: t1b = bf16(norm^2 * sum norm[s]*fb[s])   (t1b aliases ebuf — dead)
    gather_kernel<1><<<NN / 4, 256, 0, stream>>>(fb, rowptr, csr_src, norm, t1b);
    // hop 2: t2b = bf16(norm * sum t1b[s])            (t2b aliases fb — dead)
    gather_kernel<2><<<NN / 4, 256, 0, stream>>>(t1b, rowptr, csr_src, norm, t2b);

    // FC: out = t2b @ W1^T + b1  (MFMA, no LDS)
    fc_mfma_kernel<<<(6250 + 3) / 4, 256, 0, stream>>>(t2b, W1, b1, out);
}